// Round 2
// baseline (2546.939 us; speedup 1.0000x reference)
//
#include <hip/hip_runtime.h>
#include <hip/hip_bf16.h>

#define Nn 50000
#define RR 3
#define EE 300000
#define HH 4
#define DD 32

// ---------------- CSR build ----------------

__global__ void zero_kernel(int* counts, int* totals) {
    int i = blockIdx.x * blockDim.x + threadIdx.x;
    if (i < RR * Nn) counts[i] = 0;
    if (i < 4) totals[i] = 0;
}

__global__ void count_kernel(const int* edges, int* counts) {
    int i = blockIdx.x * blockDim.x + threadIdx.x;
    if (i >= RR * EE) return;
    int r = i / EE, e = i - r * EE;
    int dst = edges[(size_t)r * 2 * EE + EE + e];
    atomicAdd(&counts[r * Nn + dst], 1);
}

__global__ void alloc_kernel(const int* counts, int* row_start, int* cursor, int* totals) {
    int i = blockIdx.x * blockDim.x + threadIdx.x;
    if (i >= RR * Nn) return;
    int r = i / Nn;
    int c = counts[i];
    int s = atomicAdd(&totals[r], c);
    row_start[i] = s;
    cursor[i] = s;
}

__global__ void scatter_kernel(const int* edges, int* cursor, int* csr_src) {
    int i = blockIdx.x * blockDim.x + threadIdx.x;
    if (i >= RR * EE) return;
    int r = i / EE, e = i - r * EE;
    int src = edges[(size_t)r * 2 * EE + e];
    int dst = edges[(size_t)r * 2 * EE + EE + e];
    int slot = atomicAdd(&cursor[r * Nn + dst], 1);
    csr_src[(size_t)r * EE + slot] = src;
}

// ---------------- GEMM: A[N,128] @ W[r][128,128] -> feat[r][N][128] (fp32) ----------------
// Grid: (6, ceil(N/64)); block 256. BM=BN=64, BK=16.

template<bool RELU_A>
__global__ __launch_bounds__(256) void gemm_proj_kernel(const float* __restrict__ A,
                                                        const float* __restrict__ W,
                                                        float* __restrict__ C) {
    __shared__ float As[16][65];
    __shared__ float Bs[16][65];
    int tid = threadIdx.x;
    int row0 = blockIdx.y * 64;
    int c0 = blockIdx.x * 64;
    int r = c0 >> 7;        // relation
    int j0 = c0 & 127;      // col within relation
    float acc[4][4] = {};
    int tx = tid & 15, ty = tid >> 4;
    for (int k0 = 0; k0 < 128; k0 += 16) {
        #pragma unroll
        for (int i = 0; i < 4; ++i) {
            int lin = tid + i * 256;
            int m = lin >> 4, kk = lin & 15;
            int row = row0 + m;
            float v = 0.f;
            if (row < Nn) v = A[(size_t)row * 128 + k0 + kk];
            if (RELU_A) v = fmaxf(v, 0.f);
            As[kk][m] = v;
        }
        #pragma unroll
        for (int i = 0; i < 4; ++i) {
            int lin = tid + i * 256;
            int kk = lin >> 6, j = lin & 63;
            Bs[kk][j] = W[(size_t)r * 16384 + (size_t)(k0 + kk) * 128 + j0 + j];
        }
        __syncthreads();
        #pragma unroll
        for (int kk = 0; kk < 16; ++kk) {
            float a[4], b[4];
            #pragma unroll
            for (int i = 0; i < 4; ++i) a[i] = As[kk][ty + i * 16];
            #pragma unroll
            for (int j = 0; j < 4; ++j) b[j] = Bs[kk][tx + j * 16];
            #pragma unroll
            for (int i = 0; i < 4; ++i)
                #pragma unroll
                for (int j = 0; j < 4; ++j) acc[i][j] += a[i] * b[j];
        }
        __syncthreads();
    }
    #pragma unroll
    for (int i = 0; i < 4; ++i) {
        int row = row0 + ty + i * 16;
        if (row >= Nn) continue;
        #pragma unroll
        for (int j = 0; j < 4; ++j) {
            int col = j0 + tx + j * 16;
            C[(size_t)r * Nn * 128 + (size_t)row * 128 + col] = acc[i][j];
        }
    }
}

// ---------------- Final GEMM: A[N,128] @ Wl[128,64] + bl -> out [N,64] ----------------

__global__ __launch_bounds__(256) void gemm_final_kernel(const float* __restrict__ A,
                                                         const float* __restrict__ Wl,
                                                         const float* __restrict__ bl,
                                                         float* __restrict__ out) {
    __shared__ float As[16][65];
    __shared__ float Bs[16][65];
    int tid = threadIdx.x;
    int row0 = blockIdx.y * 64;
    float acc[4][4] = {};
    int tx = tid & 15, ty = tid >> 4;
    for (int k0 = 0; k0 < 128; k0 += 16) {
        #pragma unroll
        for (int i = 0; i < 4; ++i) {
            int lin = tid + i * 256;
            int m = lin >> 4, kk = lin & 15;
            int row = row0 + m;
            As[kk][m] = (row < Nn) ? A[(size_t)row * 128 + k0 + kk] : 0.f;
        }
        #pragma unroll
        for (int i = 0; i < 4; ++i) {
            int lin = tid + i * 256;
            int kk = lin >> 6, j = lin & 63;
            Bs[kk][j] = Wl[(size_t)(k0 + kk) * 64 + j];
        }
        __syncthreads();
        #pragma unroll
        for (int kk = 0; kk < 16; ++kk) {
            float a[4], b[4];
            #pragma unroll
            for (int i = 0; i < 4; ++i) a[i] = As[kk][ty + i * 16];
            #pragma unroll
            for (int j = 0; j < 4; ++j) b[j] = Bs[kk][tx + j * 16];
            #pragma unroll
            for (int i = 0; i < 4; ++i)
                #pragma unroll
                for (int j = 0; j < 4; ++j) acc[i][j] += a[i] * b[j];
        }
        __syncthreads();
    }
    #pragma unroll
    for (int i = 0; i < 4; ++i) {
        int row = row0 + ty + i * 16;
        if (row >= Nn) continue;
        #pragma unroll
        for (int j = 0; j < 4; ++j) {
            int col = tx + j * 16;
            out[(size_t)row * 64 + col] = acc[i][j] + bl[col];
        }
    }
}

// ---------------- el/er: [r][n][h] = dot(feat[r][n][h*32:], a[r][h][:]) ----------------

__global__ void elr_kernel(const float* __restrict__ feat, const float* __restrict__ al,
                           const float* __restrict__ ar, float* __restrict__ el,
                           float* __restrict__ er) {
    int i = blockIdx.x * blockDim.x + threadIdx.x;
    if (i >= RR * Nn * HH) return;
    int h = i & 3;
    int nr = i >> 2;
    int n = nr % Nn;
    int r = nr / Nn;
    const float* f = feat + (size_t)r * Nn * 128 + (size_t)n * 128 + h * 32;
    const float* alp = al + r * 128 + h * 32;
    const float* arp = ar + r * 128 + h * 32;
    float sl = 0.f, sr = 0.f;
    #pragma unroll
    for (int d = 0; d < 32; ++d) {
        float v = f[d];
        sl += v * alp[d];
        sr += v * arp[d];
    }
    el[i] = sl;
    er[i] = sr;
}

// ---------------- aggregation: per dst node, softmax over CSR edges, sum relations ----------------

__global__ __launch_bounds__(128) void agg_kernel(const float* __restrict__ feat,
                                                  const float* __restrict__ el,
                                                  const float* __restrict__ er,
                                                  const int* __restrict__ row_start,
                                                  const int* __restrict__ counts,
                                                  const int* __restrict__ csr_src,
                                                  const float* __restrict__ b,
                                                  float* __restrict__ out) {
    int n = blockIdx.x;
    int t = threadIdx.x;   // 0..127 -> (h = t>>5, d = t&31)
    int h = t >> 5;
    float acc = b[t] + b[128 + t] + b[256 + t];
    for (int r = 0; r < RR; ++r) {
        int base = r * Nn + n;
        int cnt = counts[base];
        if (cnt == 0) continue;
        int start = row_start[base];
        const int* srcs = csr_src + (size_t)r * EE + start;
        float erv = er[(size_t)base * 4 + h];
        const float* elr_ = el + (size_t)r * Nn * 4;
        const float* fr = feat + (size_t)r * Nn * 128;
        float m = -1e30f;
        for (int i = 0; i < cnt; ++i) {
            int s = srcs[i];
            float x = elr_[s * 4 + h] + erv;
            x = (x > 0.f) ? x : 0.2f * x;
            m = fmaxf(m, x);
        }
        float den = 0.f, num = 0.f;
        for (int i = 0; i < cnt; ++i) {
            int s = srcs[i];
            float x = elr_[s * 4 + h] + erv;
            x = (x > 0.f) ? x : 0.2f * x;
            float w = __expf(x - m);
            den += w;
            num += w * fr[(size_t)s * 128 + t];
        }
        acc += num / den;
    }
    out[(size_t)n * 128 + t] = acc;
}

// ---------------- launch ----------------

extern "C" void kernel_launch(void* const* d_in, const int* in_sizes, int n_in,
                              void* d_out, int out_size, void* d_ws, size_t ws_size,
                              hipStream_t stream) {
    const float* x   = (const float*)d_in[0];
    const int*  edges = (const int*)d_in[1];
    const float* W1  = (const float*)d_in[2];
    const float* al1 = (const float*)d_in[3];
    const float* ar1 = (const float*)d_in[4];
    const float* b1  = (const float*)d_in[5];
    const float* W2  = (const float*)d_in[6];
    const float* al2 = (const float*)d_in[7];
    const float* ar2 = (const float*)d_in[8];
    const float* b2  = (const float*)d_in[9];
    const float* Wl  = (const float*)d_in[10];
    const float* bl  = (const float*)d_in[11];
    float* out = (float*)d_out;

    // workspace layout (fp32 + int)
    float* feat   = (float*)d_ws;                       // 3*N*128
    float* el     = feat + (size_t)RR * Nn * 128;       // 3*N*4
    float* er     = el + (size_t)RR * Nn * 4;           // 3*N*4
    float* outbuf = er + (size_t)RR * Nn * 4;           // N*128
    int* counts    = (int*)(outbuf + (size_t)Nn * 128); // 3*N
    int* row_start = counts + RR * Nn;                  // 3*N
    int* cursor    = row_start + RR * Nn;               // 3*N
    int* totals    = cursor + RR * Nn;                  // 4
    int* csr_src   = totals + 4;                        // 3*E

    const int rowBlocks = (Nn + 63) / 64;  // 782

    // CSR build (shared by both layers)
    zero_kernel<<<(RR * Nn + 255) / 256, 256, 0, stream>>>(counts, totals);
    count_kernel<<<(RR * EE + 255) / 256, 256, 0, stream>>>(edges, counts);
    alloc_kernel<<<(RR * Nn + 255) / 256, 256, 0, stream>>>(counts, row_start, cursor, totals);
    scatter_kernel<<<(RR * EE + 255) / 256, 256, 0, stream>>>(edges, cursor, csr_src);

    // layer 1
    gemm_proj_kernel<false><<<dim3(6, rowBlocks), 256, 0, stream>>>(x, W1, feat);
    elr_kernel<<<(RR * Nn * HH + 255) / 256, 256, 0, stream>>>(feat, al1, ar1, el, er);
    agg_kernel<<<Nn, 128, 0, stream>>>(feat, el, er, row_start, counts, csr_src, b1, outbuf);

    // layer 2 (relu fused into A-load)
    gemm_proj_kernel<true><<<dim3(6, rowBlocks), 256, 0, stream>>>(outbuf, W2, feat);
    elr_kernel<<<(RR * Nn * HH + 255) / 256, 256, 0, stream>>>(feat, al2, ar2, el, er);
    agg_kernel<<<Nn, 128, 0, stream>>>(feat, el, er, row_start, counts, csr_src, b2, outbuf);

    // final linear
    gemm_final_kernel<<<dim3(1, rowBlocks), 256, 0, stream>>>(outbuf, Wl, bl, out);
}

// Round 3
// 817.919 us; speedup vs baseline: 3.1139x; 3.1139x over previous
//
#include <hip/hip_runtime.h>
#include <hip/hip_bf16.h>

#define Nn 50000
#define RR 3
#define EE 300000
#define HH 4
#define DD 32

// ---------------- CSR build ----------------

__global__ void zero_kernel(int* counts, int* totals) {
    int i = blockIdx.x * blockDim.x + threadIdx.x;
    if (i < RR * Nn) counts[i] = 0;
    if (i < 4) totals[i] = 0;
}

__global__ void count_kernel(const int* edges, int* counts) {
    int i = blockIdx.x * blockDim.x + threadIdx.x;
    if (i >= RR * EE) return;
    int r = i / EE, e = i - r * EE;
    int dst = edges[(size_t)r * 2 * EE + EE + e];
    atomicAdd(&counts[r * Nn + dst], 1);
}

// Grid: (ceil(N/256), R); block 256. One relation per block -> no segmentation.
// Block-local exclusive scan + ONE atomic per block (was: 1 atomic per thread on
// 3 addresses = 50k-deep serialization = 1.7 ms).
__global__ __launch_bounds__(256) void alloc_kernel(const int* __restrict__ counts,
                                                    int* __restrict__ row_start,
                                                    int* __restrict__ cursor,
                                                    int* __restrict__ totals) {
    __shared__ int s[256];
    __shared__ int base_s;
    int r = blockIdx.y;
    int tid = threadIdx.x;
    int n = blockIdx.x * 256 + tid;
    int idx = r * Nn + n;
    int c = (n < Nn) ? counts[idx] : 0;
    s[tid] = c;
    __syncthreads();
    #pragma unroll
    for (int off = 1; off < 256; off <<= 1) {
        int v = 0;
        if (tid >= off) v = s[tid - off];
        __syncthreads();
        if (tid >= off) s[tid] += v;
        __syncthreads();
    }
    if (tid == 255) base_s = atomicAdd(&totals[r], s[255]);
    __syncthreads();
    if (n < Nn) {
        int st = base_s + s[tid] - c;   // exclusive within block + block base
        row_start[idx] = st;
        cursor[idx] = st;
    }
}

__global__ void scatter_kernel(const int* edges, int* cursor, int* csr_src) {
    int i = blockIdx.x * blockDim.x + threadIdx.x;
    if (i >= RR * EE) return;
    int r = i / EE, e = i - r * EE;
    int src = edges[(size_t)r * 2 * EE + e];
    int dst = edges[(size_t)r * 2 * EE + EE + e];
    int slot = atomicAdd(&cursor[r * Nn + dst], 1);
    csr_src[(size_t)r * EE + slot] = src;
}

// ---------------- GEMM: A[N,128] @ W[r][128,128] -> feat[r][N][128] (fp32) ----------------
// Grid: (6, ceil(N/64)); block 256. BM=BN=64, BK=16.

template<bool RELU_A>
__global__ __launch_bounds__(256) void gemm_proj_kernel(const float* __restrict__ A,
                                                        const float* __restrict__ W,
                                                        float* __restrict__ C) {
    __shared__ float As[16][65];
    __shared__ float Bs[16][65];
    int tid = threadIdx.x;
    int row0 = blockIdx.y * 64;
    int c0 = blockIdx.x * 64;
    int r = c0 >> 7;        // relation
    int j0 = c0 & 127;      // col within relation
    float acc[4][4] = {};
    int tx = tid & 15, ty = tid >> 4;
    for (int k0 = 0; k0 < 128; k0 += 16) {
        #pragma unroll
        for (int i = 0; i < 4; ++i) {
            int lin = tid + i * 256;
            int m = lin >> 4, kk = lin & 15;
            int row = row0 + m;
            float v = 0.f;
            if (row < Nn) v = A[(size_t)row * 128 + k0 + kk];
            if (RELU_A) v = fmaxf(v, 0.f);
            As[kk][m] = v;
        }
        #pragma unroll
        for (int i = 0; i < 4; ++i) {
            int lin = tid + i * 256;
            int kk = lin >> 6, j = lin & 63;
            Bs[kk][j] = W[(size_t)r * 16384 + (size_t)(k0 + kk) * 128 + j0 + j];
        }
        __syncthreads();
        #pragma unroll
        for (int kk = 0; kk < 16; ++kk) {
            float a[4], b[4];
            #pragma unroll
            for (int i = 0; i < 4; ++i) a[i] = As[kk][ty + i * 16];
            #pragma unroll
            for (int j = 0; j < 4; ++j) b[j] = Bs[kk][tx + j * 16];
            #pragma unroll
            for (int i = 0; i < 4; ++i)
                #pragma unroll
                for (int j = 0; j < 4; ++j) acc[i][j] += a[i] * b[j];
        }
        __syncthreads();
    }
    #pragma unroll
    for (int i = 0; i < 4; ++i) {
        int row = row0 + ty + i * 16;
        if (row >= Nn) continue;
        #pragma unroll
        for (int j = 0; j < 4; ++j) {
            int col = j0 + tx + j * 16;
            C[(size_t)r * Nn * 128 + (size_t)row * 128 + col] = acc[i][j];
        }
    }
}

// ---------------- Final GEMM: A[N,128] @ Wl[128,64] + bl -> out [N,64] ----------------

__global__ __launch_bounds__(256) void gemm_final_kernel(const float* __restrict__ A,
                                                         const float* __restrict__ Wl,
                                                         const float* __restrict__ bl,
                                                         float* __restrict__ out) {
    __shared__ float As[16][65];
    __shared__ float Bs[16][65];
    int tid = threadIdx.x;
    int row0 = blockIdx.y * 64;
    float acc[4][4] = {};
    int tx = tid & 15, ty = tid >> 4;
    for (int k0 = 0; k0 < 128; k0 += 16) {
        #pragma unroll
        for (int i = 0; i < 4; ++i) {
            int lin = tid + i * 256;
            int m = lin >> 4, kk = lin & 15;
            int row = row0 + m;
            As[kk][m] = (row < Nn) ? A[(size_t)row * 128 + k0 + kk] : 0.f;
        }
        #pragma unroll
        for (int i = 0; i < 4; ++i) {
            int lin = tid + i * 256;
            int kk = lin >> 6, j = lin & 63;
            Bs[kk][j] = Wl[(size_t)(k0 + kk) * 64 + j];
        }
        __syncthreads();
        #pragma unroll
        for (int kk = 0; kk < 16; ++kk) {
            float a[4], b[4];
            #pragma unroll
            for (int i = 0; i < 4; ++i) a[i] = As[kk][ty + i * 16];
            #pragma unroll
            for (int j = 0; j < 4; ++j) b[j] = Bs[kk][tx + j * 16];
            #pragma unroll
            for (int i = 0; i < 4; ++i)
                #pragma unroll
                for (int j = 0; j < 4; ++j) acc[i][j] += a[i] * b[j];
        }
        __syncthreads();
    }
    #pragma unroll
    for (int i = 0; i < 4; ++i) {
        int row = row0 + ty + i * 16;
        if (row >= Nn) continue;
        #pragma unroll
        for (int j = 0; j < 4; ++j) {
            int col = tx + j * 16;
            out[(size_t)row * 64 + col] = acc[i][j] + bl[col];
        }
    }
}

// ---------------- el/er: [r][n][h] = dot(feat[r][n][h*32:], a[r][h][:]) ----------------

__global__ void elr_kernel(const float* __restrict__ feat, const float* __restrict__ al,
                           const float* __restrict__ ar, float* __restrict__ el,
                           float* __restrict__ er) {
    int i = blockIdx.x * blockDim.x + threadIdx.x;
    if (i >= RR * Nn * HH) return;
    int h = i & 3;
    int nr = i >> 2;
    int n = nr % Nn;
    int r = nr / Nn;
    const float* f = feat + (size_t)r * Nn * 128 + (size_t)n * 128 + h * 32;
    const float* alp = al + r * 128 + h * 32;
    const float* arp = ar + r * 128 + h * 32;
    float sl = 0.f, sr = 0.f;
    #pragma unroll
    for (int d = 0; d < 32; ++d) {
        float v = f[d];
        sl += v * alp[d];
        sr += v * arp[d];
    }
    el[i] = sl;
    er[i] = sr;
}

// ---------------- aggregation: per dst node, softmax over CSR edges, sum relations ----------------

__global__ __launch_bounds__(128) void agg_kernel(const float* __restrict__ feat,
                                                  const float* __restrict__ el,
                                                  const float* __restrict__ er,
                                                  const int* __restrict__ row_start,
                                                  const int* __restrict__ counts,
                                                  const int* __restrict__ csr_src,
                                                  const float* __restrict__ b,
                                                  float* __restrict__ out) {
    int n = blockIdx.x;
    int t = threadIdx.x;   // 0..127 -> (h = t>>5, d = t&31)
    int h = t >> 5;
    float acc = b[t] + b[128 + t] + b[256 + t];
    for (int r = 0; r < RR; ++r) {
        int base = r * Nn + n;
        int cnt = counts[base];
        if (cnt == 0) continue;
        int start = row_start[base];
        const int* srcs = csr_src + (size_t)r * EE + start;
        float erv = er[(size_t)base * 4 + h];
        const float* elr_ = el + (size_t)r * Nn * 4;
        const float* fr = feat + (size_t)r * Nn * 128;
        float m = -1e30f;
        for (int i = 0; i < cnt; ++i) {
            int s = srcs[i];
            float x = elr_[s * 4 + h] + erv;
            x = (x > 0.f) ? x : 0.2f * x;
            m = fmaxf(m, x);
        }
        float den = 0.f, num = 0.f;
        for (int i = 0; i < cnt; ++i) {
            int s = srcs[i];
            float x = elr_[s * 4 + h] + erv;
            x = (x > 0.f) ? x : 0.2f * x;
            float w = __expf(x - m);
            den += w;
            num += w * fr[(size_t)s * 128 + t];
        }
        acc += num / den;
    }
    out[(size_t)n * 128 + t] = acc;
}

// ---------------- launch ----------------

extern "C" void kernel_launch(void* const* d_in, const int* in_sizes, int n_in,
                              void* d_out, int out_size, void* d_ws, size_t ws_size,
                              hipStream_t stream) {
    const float* x   = (const float*)d_in[0];
    const int*  edges = (const int*)d_in[1];
    const float* W1  = (const float*)d_in[2];
    const float* al1 = (const float*)d_in[3];
    const float* ar1 = (const float*)d_in[4];
    const float* b1  = (const float*)d_in[5];
    const float* W2  = (const float*)d_in[6];
    const float* al2 = (const float*)d_in[7];
    const float* ar2 = (const float*)d_in[8];
    const float* b2  = (const float*)d_in[9];
    const float* Wl  = (const float*)d_in[10];
    const float* bl  = (const float*)d_in[11];
    float* out = (float*)d_out;

    // workspace layout (fp32 + int)
    float* feat   = (float*)d_ws;                       // 3*N*128
    float* el     = feat + (size_t)RR * Nn * 128;       // 3*N*4
    float* er     = el + (size_t)RR * Nn * 4;           // 3*N*4
    float* outbuf = er + (size_t)RR * Nn * 4;           // N*128
    int* counts    = (int*)(outbuf + (size_t)Nn * 128); // 3*N
    int* row_start = counts + RR * Nn;                  // 3*N
    int* cursor    = row_start + RR * Nn;               // 3*N
    int* totals    = cursor + RR * Nn;                  // 4
    int* csr_src   = totals + 4;                        // 3*E

    const int rowBlocks = (Nn + 63) / 64;   // 782
    const int nodeBlocks = (Nn + 255) / 256; // 196

    // CSR build (shared by both layers)
    zero_kernel<<<(RR * Nn + 255) / 256, 256, 0, stream>>>(counts, totals);
    count_kernel<<<(RR * EE + 255) / 256, 256, 0, stream>>>(edges, counts);
    alloc_kernel<<<dim3(nodeBlocks, RR), 256, 0, stream>>>(counts, row_start, cursor, totals);
    scatter_kernel<<<(RR * EE + 255) / 256, 256, 0, stream>>>(edges, cursor, csr_src);

    // layer 1
    gemm_proj_kernel<false><<<dim3(6, rowBlocks), 256, 0, stream>>>(x, W1, feat);
    elr_kernel<<<(RR * Nn * HH + 255) / 256, 256, 0, stream>>>(feat, al1, ar1, el, er);
    agg_kernel<<<Nn, 128, 0, stream>>>(feat, el, er, row_start, counts, csr_src, b1, outbuf);

    // layer 2 (relu fused into A-load)
    gemm_proj_kernel<true><<<dim3(6, rowBlocks), 256, 0, stream>>>(outbuf, W2, feat);
    elr_kernel<<<(RR * Nn * HH + 255) / 256, 256, 0, stream>>>(feat, al2, ar2, el, er);
    agg_kernel<<<Nn, 128, 0, stream>>>(feat, el, er, row_start, counts, csr_src, b2, outbuf);

    // final linear
    gemm_final_kernel<<<dim3(1, rowBlocks), 256, 0, stream>>>(outbuf, Wl, bl, out);
}

// Round 4
// 580.701 us; speedup vs baseline: 4.3860x; 1.4085x over previous
//
#include <hip/hip_runtime.h>
#include <hip/hip_bf16.h>
#include <hip/hip_fp16.h>

#define Nn 50000
#define RR 3
#define EE 300000
#define HH 4
#define DD 32

// ---------------- CSR build ----------------

__global__ void zero_kernel(int* counts, int* totals) {
    int i = blockIdx.x * blockDim.x + threadIdx.x;
    if (i < RR * Nn) counts[i] = 0;
    if (i < 4) totals[i] = 0;
}

__global__ void count_kernel(const int* edges, int* counts) {
    int i = blockIdx.x * blockDim.x + threadIdx.x;
    if (i >= RR * EE) return;
    int r = i / EE, e = i - r * EE;
    int dst = edges[(size_t)r * 2 * EE + EE + e];
    atomicAdd(&counts[r * Nn + dst], 1);
}

// Block-local scan + one atomic per block (R3 fix: was 1.7 ms of serialized atomics).
__global__ __launch_bounds__(256) void alloc_kernel(const int* __restrict__ counts,
                                                    int* __restrict__ row_start,
                                                    int* __restrict__ cursor,
                                                    int* __restrict__ totals) {
    __shared__ int s[256];
    __shared__ int base_s;
    int r = blockIdx.y;
    int tid = threadIdx.x;
    int n = blockIdx.x * 256 + tid;
    int idx = r * Nn + n;
    int c = (n < Nn) ? counts[idx] : 0;
    s[tid] = c;
    __syncthreads();
    #pragma unroll
    for (int off = 1; off < 256; off <<= 1) {
        int v = 0;
        if (tid >= off) v = s[tid - off];
        __syncthreads();
        if (tid >= off) s[tid] += v;
        __syncthreads();
    }
    if (tid == 255) base_s = atomicAdd(&totals[r], s[255]);
    __syncthreads();
    if (n < Nn) {
        int st = base_s + s[tid] - c;
        row_start[idx] = st;
        cursor[idx] = st;
    }
}

__global__ void scatter_kernel(const int* edges, int* cursor, int* csr_src) {
    int i = blockIdx.x * blockDim.x + threadIdx.x;
    if (i >= RR * EE) return;
    int r = i / EE, e = i - r * EE;
    int src = edges[(size_t)r * 2 * EE + e];
    int dst = edges[(size_t)r * 2 * EE + EE + e];
    int slot = atomicAdd(&cursor[r * Nn + dst], 1);
    csr_src[(size_t)r * EE + slot] = src;
}

// ---------------- GEMM: A[N,128] @ W[r][128,128] -> feat[r][N][128] (fp16 out) ----------------
// Grid: (6, ceil(N/64)); block 256. BM=BN=64, BK=16. 4x4 contiguous per-thread subtile.

template<bool RELU_A>
__global__ __launch_bounds__(256) void gemm_proj_kernel(const float* __restrict__ A,
                                                        const float* __restrict__ W,
                                                        __half* __restrict__ C) {
    __shared__ float As[16][65];   // [kk][m]
    __shared__ float Bs[16][65];   // [kk][j]
    int tid = threadIdx.x;
    int row0 = blockIdx.y * 64;
    int c0 = blockIdx.x * 64;
    int r = c0 >> 7;
    int j0 = c0 & 127;
    float acc[4][4] = {};
    int tx = tid & 15, ty = tid >> 4;
    for (int k0 = 0; k0 < 128; k0 += 16) {
        {   // A stage: float4 per thread
            int m = tid >> 2, c = (tid & 3) * 4;
            int row = row0 + m;
            float4 v = make_float4(0.f, 0.f, 0.f, 0.f);
            if (row < Nn) v = *(const float4*)&A[(size_t)row * 128 + k0 + c];
            if (RELU_A) {
                v.x = fmaxf(v.x, 0.f); v.y = fmaxf(v.y, 0.f);
                v.z = fmaxf(v.z, 0.f); v.w = fmaxf(v.w, 0.f);
            }
            As[c + 0][m] = v.x; As[c + 1][m] = v.y; As[c + 2][m] = v.z; As[c + 3][m] = v.w;
        }
        {   // B stage: float4 per thread, contiguous LDS write
            int kk = tid >> 4, j = (tid & 15) * 4;
            float4 v = *(const float4*)&W[(size_t)r * 16384 + (size_t)(k0 + kk) * 128 + j0 + j];
            *(float4*)&Bs[kk][j] = v;
        }
        __syncthreads();
        #pragma unroll
        for (int kk = 0; kk < 16; ++kk) {
            float4 a = *(const float4*)&As[kk][ty * 4];
            float4 b = *(const float4*)&Bs[kk][tx * 4];
            float av[4] = {a.x, a.y, a.z, a.w};
            float bv[4] = {b.x, b.y, b.z, b.w};
            #pragma unroll
            for (int i = 0; i < 4; ++i)
                #pragma unroll
                for (int j = 0; j < 4; ++j) acc[i][j] += av[i] * bv[j];
        }
        __syncthreads();
    }
    #pragma unroll
    for (int i = 0; i < 4; ++i) {
        int row = row0 + ty * 4 + i;
        if (row >= Nn) continue;
        __half2 h0 = __floats2half2_rn(acc[i][0], acc[i][1]);
        __half2 h1 = __floats2half2_rn(acc[i][2], acc[i][3]);
        __half2* dst = (__half2*)&C[(size_t)r * Nn * 128 + (size_t)row * 128 + j0 + tx * 4];
        dst[0] = h0; dst[1] = h1;
    }
}

// ---------------- Final GEMM: A[N,128] @ Wl[128,64] + bl -> out [N,64] fp32 ----------------

__global__ __launch_bounds__(256) void gemm_final_kernel(const float* __restrict__ A,
                                                         const float* __restrict__ Wl,
                                                         const float* __restrict__ bl,
                                                         float* __restrict__ out) {
    __shared__ float As[16][65];
    __shared__ float Bs[16][65];
    int tid = threadIdx.x;
    int row0 = blockIdx.x * 64;
    float acc[4][4] = {};
    int tx = tid & 15, ty = tid >> 4;
    for (int k0 = 0; k0 < 128; k0 += 16) {
        {
            int m = tid >> 2, c = (tid & 3) * 4;
            int row = row0 + m;
            float4 v = make_float4(0.f, 0.f, 0.f, 0.f);
            if (row < Nn) v = *(const float4*)&A[(size_t)row * 128 + k0 + c];
            As[c + 0][m] = v.x; As[c + 1][m] = v.y; As[c + 2][m] = v.z; As[c + 3][m] = v.w;
        }
        {
            int kk = tid >> 4, j = (tid & 15) * 4;
            float4 v = *(const float4*)&Wl[(size_t)(k0 + kk) * 64 + j];
            *(float4*)&Bs[kk][j] = v;
        }
        __syncthreads();
        #pragma unroll
        for (int kk = 0; kk < 16; ++kk) {
            float4 a = *(const float4*)&As[kk][ty * 4];
            float4 b = *(const float4*)&Bs[kk][tx * 4];
            float av[4] = {a.x, a.y, a.z, a.w};
            float bv[4] = {b.x, b.y, b.z, b.w};
            #pragma unroll
            for (int i = 0; i < 4; ++i)
                #pragma unroll
                for (int j = 0; j < 4; ++j) acc[i][j] += av[i] * bv[j];
        }
        __syncthreads();
    }
    float4 bias = *(const float4*)&bl[tx * 4];
    #pragma unroll
    for (int i = 0; i < 4; ++i) {
        int row = row0 + ty * 4 + i;
        if (row >= Nn) continue;
        float4 v = make_float4(acc[i][0] + bias.x, acc[i][1] + bias.y,
                               acc[i][2] + bias.z, acc[i][3] + bias.w);
        *(float4*)&out[(size_t)row * 64 + tx * 4] = v;
    }
}

// ---------------- el/er from fp16 feat ----------------

__global__ void elr_kernel(const __half2* __restrict__ feat2, const float* __restrict__ al,
                           const float* __restrict__ ar, float* __restrict__ el,
                           float* __restrict__ er) {
    int i = blockIdx.x * blockDim.x + threadIdx.x;
    if (i >= RR * Nn * HH) return;
    int h = i & 3;
    int nr = i >> 2;
    int n = nr % Nn;
    int r = nr / Nn;
    const __half2* f = feat2 + ((size_t)(r * Nn + n) * 64 + h * 16);
    const float* alp = al + r * 128 + h * 32;
    const float* arp = ar + r * 128 + h * 32;
    float sl = 0.f, sr = 0.f;
    #pragma unroll
    for (int d = 0; d < 16; ++d) {
        float2 v = __half22float2(f[d]);
        sl += v.x * alp[2 * d] + v.y * alp[2 * d + 1];
        sr += v.x * arp[2 * d] + v.y * arp[2 * d + 1];
    }
    el[i] = sl;
    er[i] = sr;
}

// ---------------- aggregation: one wave per dst node, single-pass (no max) softmax ----------------
// exp(e)/sum(exp(e)) == exp(e-max)/sum(exp(e-max)); |e| <~ 1.5 here so no overflow risk.

__global__ __launch_bounds__(256) void agg_kernel(const __half2* __restrict__ feat2,
                                                  const float* __restrict__ el,
                                                  const float* __restrict__ er,
                                                  const int* __restrict__ row_start,
                                                  const int* __restrict__ counts,
                                                  const int* __restrict__ csr_src,
                                                  const float* __restrict__ b,
                                                  float* __restrict__ out) {
    int wave = threadIdx.x >> 6;
    int lane = threadIdx.x & 63;
    int n = blockIdx.x * 4 + wave;
    if (n >= Nn) return;
    int h = lane >> 4;                  // head for d-values {2*lane, 2*lane+1}
    int t2 = lane * 2;
    float accx = b[t2] + b[128 + t2] + b[256 + t2];
    float accy = b[t2 + 1] + b[128 + t2 + 1] + b[256 + t2 + 1];
    for (int r = 0; r < RR; ++r) {
        int base = r * Nn + n;
        int cnt = counts[base];
        if (cnt == 0) continue;
        const int* srcs = csr_src + (size_t)r * EE + row_start[base];
        float erv = er[(size_t)base * 4 + h];
        const float* elr_ = el + (size_t)r * Nn * 4;
        const __half2* fr = feat2 + (size_t)r * Nn * 64;
        float den = 0.f, numx = 0.f, numy = 0.f;
        for (int i0 = 0; i0 < cnt; i0 += 64) {
            int s_l = 0;
            if (i0 + lane < cnt) s_l = srcs[i0 + lane];
            int m = cnt - i0; if (m > 64) m = 64;
            int j = 0;
            for (; j + 1 < m; j += 2) {
                int s0 = __shfl(s_l, j);
                int s1 = __shfl(s_l, j + 1);
                float x0 = elr_[(size_t)s0 * 4 + h] + erv;
                float x1 = elr_[(size_t)s1 * 4 + h] + erv;
                __half2 f0 = fr[(size_t)s0 * 64 + lane];
                __half2 f1 = fr[(size_t)s1 * 64 + lane];
                x0 = (x0 > 0.f) ? x0 : 0.2f * x0;
                x1 = (x1 > 0.f) ? x1 : 0.2f * x1;
                float w0 = __expf(x0), w1 = __expf(x1);
                float2 g0 = __half22float2(f0), g1 = __half22float2(f1);
                den += w0 + w1;
                numx += w0 * g0.x + w1 * g1.x;
                numy += w0 * g0.y + w1 * g1.y;
            }
            if (j < m) {
                int s0 = __shfl(s_l, j);
                float x0 = elr_[(size_t)s0 * 4 + h] + erv;
                __half2 f0 = fr[(size_t)s0 * 64 + lane];
                x0 = (x0 > 0.f) ? x0 : 0.2f * x0;
                float w0 = __expf(x0);
                float2 g0 = __half22float2(f0);
                den += w0; numx += w0 * g0.x; numy += w0 * g0.y;
            }
        }
        float inv = 1.f / den;
        accx += numx * inv;
        accy += numy * inv;
    }
    *(float2*)&out[(size_t)n * 128 + t2] = make_float2(accx, accy);
}

// ---------------- launch ----------------

extern "C" void kernel_launch(void* const* d_in, const int* in_sizes, int n_in,
                              void* d_out, int out_size, void* d_ws, size_t ws_size,
                              hipStream_t stream) {
    const float* x   = (const float*)d_in[0];
    const int*  edges = (const int*)d_in[1];
    const float* W1  = (const float*)d_in[2];
    const float* al1 = (const float*)d_in[3];
    const float* ar1 = (const float*)d_in[4];
    const float* b1  = (const float*)d_in[5];
    const float* W2  = (const float*)d_in[6];
    const float* al2 = (const float*)d_in[7];
    const float* ar2 = (const float*)d_in[8];
    const float* b2  = (const float*)d_in[9];
    const float* Wl  = (const float*)d_in[10];
    const float* bl  = (const float*)d_in[11];
    float* out = (float*)d_out;

    // workspace layout
    __half* feat  = (__half*)d_ws;                          // 3*N*128 fp16
    float* el     = (float*)(feat + (size_t)RR * Nn * 128); // 3*N*4
    float* er     = el + (size_t)RR * Nn * 4;               // 3*N*4
    float* outbuf = er + (size_t)RR * Nn * 4;               // N*128 fp32
    int* counts    = (int*)(outbuf + (size_t)Nn * 128);     // 3*N
    int* row_start = counts + RR * Nn;                      // 3*N
    int* cursor    = row_start + RR * Nn;                   // 3*N
    int* totals    = cursor + RR * Nn;                      // 4
    int* csr_src   = totals + 4;                            // 3*E

    const int rowBlocks  = (Nn + 63) / 64;    // 782
    const int nodeBlocks = (Nn + 255) / 256;  // 196
    const int aggBlocks  = (Nn + 3) / 4;      // 12500

    // CSR build (shared by both layers)
    zero_kernel<<<(RR * Nn + 255) / 256, 256, 0, stream>>>(counts, totals);
    count_kernel<<<(RR * EE + 255) / 256, 256, 0, stream>>>(edges, counts);
    alloc_kernel<<<dim3(nodeBlocks, RR), 256, 0, stream>>>(counts, row_start, cursor, totals);
    scatter_kernel<<<(RR * EE + 255) / 256, 256, 0, stream>>>(edges, cursor, csr_src);

    // layer 1
    gemm_proj_kernel<false><<<dim3(6, rowBlocks), 256, 0, stream>>>(x, W1, feat);
    elr_kernel<<<(RR * Nn * HH + 255) / 256, 256, 0, stream>>>((const __half2*)feat, al1, ar1, el, er);
    agg_kernel<<<aggBlocks, 256, 0, stream>>>((const __half2*)feat, el, er, row_start, counts, csr_src, b1, outbuf);

    // layer 2 (relu fused into A-load)
    gemm_proj_kernel<true><<<dim3(6, rowBlocks), 256, 0, stream>>>(outbuf, W2, feat);
    elr_kernel<<<(RR * Nn * HH + 255) / 256, 256, 0, stream>>>((const __half2*)feat, al2, ar2, el, er);
    agg_kernel<<<aggBlocks, 256, 0, stream>>>((const __half2*)feat, el, er, row_start, counts, csr_src, b2, outbuf);

    // final linear
    gemm_final_kernel<<<rowBlocks, 256, 0, stream>>>(outbuf, Wl, bl, out);
}

// Round 5
// 434.344 us; speedup vs baseline: 5.8639x; 1.3370x over previous
//
#include <hip/hip_runtime.h>
#include <hip/hip_bf16.h>
#include <hip/hip_fp16.h>

#define Nn 50000
#define RR 3
#define EE 300000

typedef __attribute__((ext_vector_type(8))) short short8;
typedef __attribute__((ext_vector_type(4))) short short4v;
typedef __attribute__((ext_vector_type(4))) float floatx4;

__device__ __forceinline__ short f2bf(float f) {
    __hip_bfloat16 h = __float2bfloat16(f);
    return *reinterpret_cast<short*>(&h);
}

// ---------------- CSR build ----------------

__global__ void zero_kernel(int* counts, int* totals) {
    int i = blockIdx.x * blockDim.x + threadIdx.x;
    if (i < RR * Nn) counts[i] = 0;
    if (i < 4) totals[i] = 0;
}

__global__ void count_kernel(const int* edges, int* counts) {
    int i = blockIdx.x * blockDim.x + threadIdx.x;
    if (i >= RR * EE) return;
    int r = i / EE, e = i - r * EE;
    int dst = edges[(size_t)r * 2 * EE + EE + e];
    atomicAdd(&counts[r * Nn + dst], 1);
}

__global__ __launch_bounds__(256) void alloc_kernel(const int* __restrict__ counts,
                                                    int* __restrict__ row_start,
                                                    int* __restrict__ cursor,
                                                    int* __restrict__ totals) {
    __shared__ int s[256];
    __shared__ int base_s;
    int r = blockIdx.y;
    int tid = threadIdx.x;
    int n = blockIdx.x * 256 + tid;
    int idx = r * Nn + n;
    int c = (n < Nn) ? counts[idx] : 0;
    s[tid] = c;
    __syncthreads();
    #pragma unroll
    for (int off = 1; off < 256; off <<= 1) {
        int v = 0;
        if (tid >= off) v = s[tid - off];
        __syncthreads();
        if (tid >= off) s[tid] += v;
        __syncthreads();
    }
    if (tid == 255) base_s = atomicAdd(&totals[r], s[255]);
    __syncthreads();
    if (n < Nn) {
        int st = base_s + s[tid] - c;
        row_start[idx] = st;
        cursor[idx] = st;
    }
}

__global__ void scatter_kernel(const int* edges, int* cursor, int* csr_src) {
    int i = blockIdx.x * blockDim.x + threadIdx.x;
    if (i >= RR * EE) return;
    int r = i / EE, e = i - r * EE;
    int src = edges[(size_t)r * 2 * EE + e];
    int dst = edges[(size_t)r * 2 * EE + EE + e];
    int slot = atomicAdd(&cursor[r * Nn + dst], 1);
    csr_src[(size_t)r * EE + slot] = src;
}

// ---------------- W pre-swizzle into MFMA B-fragment layout ----------------
// Z layout: [layer][r][kt][nt][lane][j] bf16; B[n = nt*16 + (lane&15)][k = kt*32 + (lane>>4)*8 + j]

__global__ void wswz_kernel(const float* __restrict__ W1, const float* __restrict__ W2,
                            short* __restrict__ Z) {
    int idx = blockIdx.x * 256 + threadIdx.x;   // 2 layers * 3r * 4kt * 8nt * 64 lanes = 12288
    if (idx >= 12288) return;
    int lane = idx & 63;
    int nt = (idx >> 6) & 7;
    int kt = (idx >> 9) & 3;
    int rl = idx >> 11;            // 0..5
    int layer = rl / 3, r = rl % 3;
    const float* W = (layer ? W2 : W1) + (size_t)r * 16384;
    int n = nt * 16 + (lane & 15);
    int k0 = kt * 32 + (lane >> 4) * 8;
    short8 v;
    #pragma unroll
    for (int j = 0; j < 8; ++j) v[j] = f2bf(W[(size_t)(k0 + j) * 128 + n]);
    *(short8*)&Z[(size_t)idx * 8] = v;
}

// ---------------- MFMA GEMM: A[N,128] @ W[r][128,128] -> feat[r][N][128] fp16 ----------------
// Grid: ceil(N/64) blocks of 256 (4 waves). Each block: stage 64x128 A tile as bf16 once,
// loop r over 3 relations; B-frags loaded global->VGPR from pre-swizzled Z (L2-resident).

template<bool RELU_A>
__global__ __launch_bounds__(256) void gemm_proj_mfma(const float* __restrict__ A,
                                                      const short* __restrict__ Z,
                                                      __half* __restrict__ C) {
    __shared__ short A_lds[64 * 136];   // row stride 136 shorts = 272 B (16B-aligned rows)
    int tid = threadIdx.x;
    int row0 = blockIdx.x * 64;
    // stage A (fp32 -> bf16), coalesced float4 loads
    #pragma unroll
    for (int p = 0; p < 8; ++p) {
        int f = p * 256 + tid;      // float4 index in 64x128 tile
        int row = f >> 5;
        int c4 = (f & 31) * 4;
        float4 v = make_float4(0.f, 0.f, 0.f, 0.f);
        if (row0 + row < Nn) v = *(const float4*)&A[(size_t)(row0 + row) * 128 + c4];
        if (RELU_A) {
            v.x = fmaxf(v.x, 0.f); v.y = fmaxf(v.y, 0.f);
            v.z = fmaxf(v.z, 0.f); v.w = fmaxf(v.w, 0.f);
        }
        short4v sv;
        sv[0] = f2bf(v.x); sv[1] = f2bf(v.y); sv[2] = f2bf(v.z); sv[3] = f2bf(v.w);
        *(short4v*)&A_lds[row * 136 + c4] = sv;
    }
    __syncthreads();
    int wave = tid >> 6, lane = tid & 63;
    int m = lane & 15, q = lane >> 4;
    // hoist A fragments (wave covers rows wave*16 .. wave*16+15); only 4 b128 reads/lane total
    short8 af[4];
    #pragma unroll
    for (int kt = 0; kt < 4; ++kt)
        af[kt] = *(short8*)&A_lds[(wave * 16 + m) * 136 + kt * 32 + q * 8];
    for (int r = 0; r < RR; ++r) {
        floatx4 acc[8];
        #pragma unroll
        for (int nt = 0; nt < 8; ++nt) acc[nt] = (floatx4)(0.f);
        const short* Zr = Z + (size_t)r * 16384;
        #pragma unroll
        for (int kt = 0; kt < 4; ++kt) {
            #pragma unroll
            for (int nt = 0; nt < 8; ++nt) {
                short8 bf = *(const short8*)&Zr[(size_t)(kt * 8 + nt) * 512 + lane * 8];
                acc[nt] = __builtin_amdgcn_mfma_f32_16x16x32_bf16(af[kt], bf, acc[nt], 0, 0, 0);
            }
        }
        __half* Cr = C + (size_t)r * Nn * 128;
        #pragma unroll
        for (int nt = 0; nt < 8; ++nt) {
            int col = nt * 16 + m;
            #pragma unroll
            for (int reg = 0; reg < 4; ++reg) {
                int row = row0 + wave * 16 + q * 4 + reg;
                if (row < Nn) Cr[(size_t)row * 128 + col] = __float2half(acc[nt][reg]);
            }
        }
    }
}

// ---------------- Final GEMM: A[N,128] @ Wl[128,64] + bl -> out [N,64] fp32 ----------------

__global__ __launch_bounds__(256) void gemm_final_kernel(const float* __restrict__ A,
                                                         const float* __restrict__ Wl,
                                                         const float* __restrict__ bl,
                                                         float* __restrict__ out) {
    __shared__ float As[16][65];
    __shared__ float Bs[16][65];
    int tid = threadIdx.x;
    int row0 = blockIdx.x * 64;
    float acc[4][4] = {};
    int tx = tid & 15, ty = tid >> 4;
    for (int k0 = 0; k0 < 128; k0 += 16) {
        {
            int mm = tid >> 2, c = (tid & 3) * 4;
            int row = row0 + mm;
            float4 v = make_float4(0.f, 0.f, 0.f, 0.f);
            if (row < Nn) v = *(const float4*)&A[(size_t)row * 128 + k0 + c];
            As[c + 0][mm] = v.x; As[c + 1][mm] = v.y; As[c + 2][mm] = v.z; As[c + 3][mm] = v.w;
        }
        {
            int kk = tid >> 4, j = (tid & 15) * 4;
            float4 v = *(const float4*)&Wl[(size_t)(k0 + kk) * 64 + j];
            *(float4*)&Bs[kk][j] = v;
        }
        __syncthreads();
        #pragma unroll
        for (int kk = 0; kk < 16; ++kk) {
            float4 a = *(const float4*)&As[kk][ty * 4];
            float4 b = *(const float4*)&Bs[kk][tx * 4];
            float av[4] = {a.x, a.y, a.z, a.w};
            float bv[4] = {b.x, b.y, b.z, b.w};
            #pragma unroll
            for (int i = 0; i < 4; ++i)
                #pragma unroll
                for (int j = 0; j < 4; ++j) acc[i][j] += av[i] * bv[j];
        }
        __syncthreads();
    }
    float4 bias = *(const float4*)&bl[tx * 4];
    #pragma unroll
    for (int i = 0; i < 4; ++i) {
        int row = row0 + ty * 4 + i;
        if (row >= Nn) continue;
        float4 v = make_float4(acc[i][0] + bias.x, acc[i][1] + bias.y,
                               acc[i][2] + bias.z, acc[i][3] + bias.w);
        *(float4*)&out[(size_t)row * 64 + tx * 4] = v;
    }
}

// ---------------- el/er from fp16 feat ----------------

__global__ void elr_kernel(const __half2* __restrict__ feat2, const float* __restrict__ al,
                           const float* __restrict__ ar, float* __restrict__ el,
                           float* __restrict__ er) {
    int i = blockIdx.x * blockDim.x + threadIdx.x;
    if (i >= RR * Nn * 4) return;
    int h = i & 3;
    int nr = i >> 2;
    int n = nr % Nn;
    int r = nr / Nn;
    const __half2* f = feat2 + ((size_t)(r * Nn + n) * 64 + h * 16);
    const float* alp = al + r * 128 + h * 32;
    const float* arp = ar + r * 128 + h * 32;
    float sl = 0.f, sr = 0.f;
    #pragma unroll
    for (int d = 0; d < 16; ++d) {
        float2 v = __half22float2(f[d]);
        sl += v.x * alp[2 * d] + v.y * alp[2 * d + 1];
        sr += v.x * arp[2 * d] + v.y * arp[2 * d + 1];
    }
    el[i] = sl;
    er[i] = sr;
}

// ---------------- aggregation: one wave per dst node, single-pass (no max) softmax ----------------

__global__ __launch_bounds__(256) void agg_kernel(const __half2* __restrict__ feat2,
                                                  const float* __restrict__ el,
                                                  const float* __restrict__ er,
                                                  const int* __restrict__ row_start,
                                                  const int* __restrict__ counts,
                                                  const int* __restrict__ csr_src,
                                                  const float* __restrict__ b,
                                                  float* __restrict__ out) {
    int wave = threadIdx.x >> 6;
    int lane = threadIdx.x & 63;
    int n = blockIdx.x * 4 + wave;
    if (n >= Nn) return;
    int h = lane >> 4;
    int t2 = lane * 2;
    float accx = b[t2] + b[128 + t2] + b[256 + t2];
    float accy = b[t2 + 1] + b[128 + t2 + 1] + b[256 + t2 + 1];
    for (int r = 0; r < RR; ++r) {
        int base = r * Nn + n;
        int cnt = counts[base];
        if (cnt == 0) continue;
        const int* srcs = csr_src + (size_t)r * EE + row_start[base];
        float erv = er[(size_t)base * 4 + h];
        const float* elr_ = el + (size_t)r * Nn * 4;
        const __half2* fr = feat2 + (size_t)r * Nn * 64;
        float den = 0.f, numx = 0.f, numy = 0.f;
        for (int i0 = 0; i0 < cnt; i0 += 64) {
            int s_l = 0;
            if (i0 + lane < cnt) s_l = srcs[i0 + lane];
            int mm = cnt - i0; if (mm > 64) mm = 64;
            int j = 0;
            for (; j + 1 < mm; j += 2) {
                int s0 = __shfl(s_l, j);
                int s1 = __shfl(s_l, j + 1);
                float x0 = elr_[(size_t)s0 * 4 + h] + erv;
                float x1 = elr_[(size_t)s1 * 4 + h] + erv;
                __half2 f0 = fr[(size_t)s0 * 64 + lane];
                __half2 f1 = fr[(size_t)s1 * 64 + lane];
                x0 = (x0 > 0.f) ? x0 : 0.2f * x0;
                x1 = (x1 > 0.f) ? x1 : 0.2f * x1;
                float w0 = __expf(x0), w1 = __expf(x1);
                float2 g0 = __half22float2(f0), g1 = __half22float2(f1);
                den += w0 + w1;
                numx += w0 * g0.x + w1 * g1.x;
                numy += w0 * g0.y + w1 * g1.y;
            }
            if (j < mm) {
                int s0 = __shfl(s_l, j);
                float x0 = elr_[(size_t)s0 * 4 + h] + erv;
                __half2 f0 = fr[(size_t)s0 * 64 + lane];
                x0 = (x0 > 0.f) ? x0 : 0.2f * x0;
                float w0 = __expf(x0);
                float2 g0 = __half22float2(f0);
                den += w0; numx += w0 * g0.x; numy += w0 * g0.y;
            }
        }
        float inv = 1.f / den;
        accx += numx * inv;
        accy += numy * inv;
    }
    *(float2*)&out[(size_t)n * 128 + t2] = make_float2(accx, accy);
}

// ---------------- launch ----------------

extern "C" void kernel_launch(void* const* d_in, const int* in_sizes, int n_in,
                              void* d_out, int out_size, void* d_ws, size_t ws_size,
                              hipStream_t stream) {
    const float* x   = (const float*)d_in[0];
    const int*  edges = (const int*)d_in[1];
    const float* W1  = (const float*)d_in[2];
    const float* al1 = (const float*)d_in[3];
    const float* ar1 = (const float*)d_in[4];
    const float* b1  = (const float*)d_in[5];
    const float* W2  = (const float*)d_in[6];
    const float* al2 = (const float*)d_in[7];
    const float* ar2 = (const float*)d_in[8];
    const float* b2  = (const float*)d_in[9];
    const float* Wl  = (const float*)d_in[10];
    const float* bl  = (const float*)d_in[11];
    float* out = (float*)d_out;

    // workspace layout
    __half* feat  = (__half*)d_ws;                          // 3*N*128 fp16
    short* Z      = (short*)(feat + (size_t)RR * Nn * 128); // 2*3*4*8*64*8 = 98304 bf16
    float* el     = (float*)(Z + 98304);                    // 3*N*4
    float* er     = el + (size_t)RR * Nn * 4;               // 3*N*4
    float* outbuf = er + (size_t)RR * Nn * 4;               // N*128 fp32
    int* counts    = (int*)(outbuf + (size_t)Nn * 128);     // 3*N
    int* row_start = counts + RR * Nn;                      // 3*N
    int* cursor    = row_start + RR * Nn;                   // 3*N
    int* totals    = cursor + RR * Nn;                      // 4
    int* csr_src   = totals + 4;                            // 3*E

    const int rowBlocks  = (Nn + 63) / 64;    // 782
    const int nodeBlocks = (Nn + 255) / 256;  // 196
    const int aggBlocks  = (Nn + 3) / 4;      // 12500

    // weight swizzle + CSR build (independent)
    wswz_kernel<<<48, 256, 0, stream>>>(W1, W2, Z);
    zero_kernel<<<(RR * Nn + 255) / 256, 256, 0, stream>>>(counts, totals);
    count_kernel<<<(RR * EE + 255) / 256, 256, 0, stream>>>(edges, counts);
    alloc_kernel<<<dim3(nodeBlocks, RR), 256, 0, stream>>>(counts, row_start, cursor, totals);
    scatter_kernel<<<(RR * EE + 255) / 256, 256, 0, stream>>>(edges, cursor, csr_src);

    // layer 1
    gemm_proj_mfma<false><<<rowBlocks, 256, 0, stream>>>(x, Z, feat);
    elr_kernel<<<(RR * Nn * 4 + 255) / 256, 256, 0, stream>>>((const __half2*)feat, al1, ar1, el, er);
    agg_kernel<<<aggBlocks, 256, 0, stream>>>((const __half2*)feat, el, er, row_start, counts, csr_src, b1, outbuf);

    // layer 2 (relu fused into A-stage)
    gemm_proj_mfma<true><<<rowBlocks, 256, 0, stream>>>(outbuf, Z + 49152, feat);
    elr_kernel<<<(RR * Nn * 4 + 255) / 256, 256, 0, stream>>>((const __half2*)feat, al2, ar2, el, er);
    agg_kernel<<<aggBlocks, 256, 0, stream>>>((const __half2*)feat, el, er, row_start, counts, csr_src, b2, outbuf);

    // final linear
    gemm_final_kernel<<<rowBlocks, 256, 0, stream>>>(outbuf, Wl, bl, out);
}